// Round 3
// baseline (1055.643 us; speedup 1.0000x reference)
//
#include <hip/hip_runtime.h>

#define B_   8
#define S_   512
#define V_   32000
#define CTX_ 8
#define NC_  512
#define D_   256
#define NH_  4
#define L_   4
#define FF_  512
#define HD_  64
#define BS_  4096   // B_*S_

#define FLG_RELU 1
#define FLG_HEAD 2
#define FLG_VT   4
#define FLG_POS  8
#define FLG_NT   16

typedef __attribute__((ext_vector_type(8))) short bf16x8;
typedef __attribute__((ext_vector_type(4))) float f32x4;

__device__ inline void gload16(const void* g, void* lds) {
    __builtin_amdgcn_global_load_lds(
        (const __attribute__((address_space(1))) void*)g,
        (__attribute__((address_space(3))) void*)lds, 16, 0, 0);
}

__device__ inline ushort f2b(float f) {   // f32 -> bf16 RNE
    union { float f; unsigned u; } v; v.f = f;
    unsigned u = v.u;
    unsigned r = u + 0x7fffu + ((u >> 16) & 1u);
    return (ushort)(r >> 16);
}

// ===========================================================================
// FAST PATH KERNELS (bf16 MFMA)
// ===========================================================================

// Embedding -> bf16 scores [BS][NC], pre-scaled by 1/8 (mean)
__global__ __launch_bounds__(256) void embed_bf16_kernel(
    const int* __restrict__ tok, const float* __restrict__ table,
    ushort* __restrict__ scores)
{
    int bs = blockIdx.x;
    int b = bs >> 9, s = bs & 511;
    int j = threadIdx.x;
    float a0 = 0.f, a1 = 0.f;
    #pragma unroll
    for (int c = 0; c < CTX_; ++c) {
        int pos = s + c - (CTX_ - 1);
        int t = (pos < 0) ? 0 : tok[b * S_ + pos];
        const float* row = table + (size_t)t * NC_;
        a0 += row[j];
        a1 += row[j + 256];
    }
    scores[(size_t)bs * NC_ + j]       = f2b(a0 * 0.125f);
    scores[(size_t)bs * NC_ + j + 256] = f2b(a1 * 0.125f);
}

// LayerNorm f32 -> bf16, one row per block
__global__ __launch_bounds__(256) void ln_bf16_kernel(
    const float* __restrict__ x, const float* __restrict__ sc,
    const float* __restrict__ bi, ushort* __restrict__ out)
{
    __shared__ float red[256];
    int row = blockIdx.x;
    int t = threadIdx.x;
    float v = x[(size_t)row * D_ + t];
    red[t] = v;
    __syncthreads();
    for (int o = 128; o > 0; o >>= 1) { if (t < o) red[t] += red[t + o]; __syncthreads(); }
    float mean = red[0] * (1.f / D_);
    __syncthreads();
    float d = v - mean;
    red[t] = d * d;
    __syncthreads();
    for (int o = 128; o > 0; o >>= 1) { if (t < o) red[t] += red[t + o]; __syncthreads(); }
    float var = red[0] * (1.f / D_);
    float r = rsqrtf(var + 1e-5f);
    out[(size_t)row * D_ + t] = f2b(d * r * sc[t] + bi[t]);
}

// Transpose+convert: W[K][N] f32 (layer z) -> Wb[N][K] bf16
__global__ void transpose_bf16_kernel(const float* __restrict__ W,
                                      ushort* __restrict__ Wb, int K, int N)
{
    int l = blockIdx.z;
    W  += (size_t)l * K * N;
    Wb += (size_t)l * K * N;
    __shared__ float tile[32][33];
    int n0 = blockIdx.x * 32, k0 = blockIdx.y * 32;
    for (int i = threadIdx.y; i < 32; i += 8)
        tile[i][threadIdx.x] = W[(size_t)(k0 + i) * N + n0 + threadIdx.x];
    __syncthreads();
    for (int i = threadIdx.y; i < 32; i += 8)
        Wb[(size_t)(n0 + i) * K + k0 + threadIdx.x] = f2b(tile[threadIdx.x][i]);
}

// f32 -> bf16 elementwise
__global__ __launch_bounds__(256) void f32_to_bf16_kernel(
    const float* __restrict__ in, ushort* __restrict__ out, int n4)
{
    int i = blockIdx.x * 256 + threadIdx.x;
    if (i >= n4) return;
    float4 v = reinterpret_cast<const float4*>(in)[i];
    ushort4 o;
    o.x = f2b(v.x); o.y = f2b(v.y); o.z = f2b(v.z); o.w = f2b(v.w);
    reinterpret_cast<ushort4*>(out)[i] = o;
}

// ---------------------------------------------------------------------------
// Unified bf16 MFMA GEMM. M fixed 4096. A[M][K] bf16, Bt[N][K] bf16.
// 128x128 tile, BK=64, 4 waves (2x2 of 64x64). N % 128 == 0, K % 64 == 0.
// flags: RELU | HEAD(qkv layout) | VT(transposed v layout) | POS | NT
// ---------------------------------------------------------------------------
__global__ __launch_bounds__(256) void mfma_gemm_kernel(
    const ushort* __restrict__ A, const ushort* __restrict__ Bt,
    const float* __restrict__ bias, const float* __restrict__ extra,
    const float* __restrict__ resid, const float* __restrict__ pos,
    float* __restrict__ Cf, ushort* __restrict__ Cb,
    int N, int K, float alpha, int flags)
{
    __shared__ ushort As[128 * 64];
    __shared__ ushort Bs[128 * 64];
    int bid = blockIdx.x;
    int nwg = gridDim.x;
    int swz = bid;
    if ((nwg & 7) == 0) { int cpx = nwg >> 3; swz = (bid & 7) * cpx + (bid >> 3); }
    int mt = swz & 31;            // M=4096 -> 32 m-tiles, m fastest
    int nt = swz >> 5;
    int row0 = mt << 7, col0 = nt << 7;
    int t = threadIdx.x;
    int w = t >> 6, lane = t & 63;
    int wr = w >> 1, wc = w & 1;

    f32x4 acc[4][4] = {};
    int srow = lane >> 3;
    int scol = (lane & 7) * 8;

    for (int k0 = 0; k0 < K; k0 += 64) {
        #pragma unroll
        for (int c = 0; c < 4; ++c) {
            int chunk = w * 4 + c;
            int r = chunk * 8 + srow;
            gload16(A  + (size_t)(row0 + r) * K + k0 + scol, As + chunk * 512);
            gload16(Bt + (size_t)(col0 + r) * K + k0 + scol, Bs + chunk * 512);
        }
        __syncthreads();
        const ushort* Ab = As + ((wr * 64 + (lane & 15)) * 64) + (lane >> 4) * 8;
        const ushort* Bb = Bs + ((wc * 64 + (lane & 15)) * 64) + (lane >> 4) * 8;
        #pragma unroll
        for (int kk = 0; kk < 2; ++kk) {
            bf16x8 a[4], b[4];
            #pragma unroll
            for (int m = 0; m < 4; ++m)
                a[m] = *reinterpret_cast<const bf16x8*>(Ab + m * 16 * 64 + kk * 32);
            #pragma unroll
            for (int n = 0; n < 4; ++n)
                b[n] = *reinterpret_cast<const bf16x8*>(Bb + n * 16 * 64 + kk * 32);
            #pragma unroll
            for (int m = 0; m < 4; ++m)
                #pragma unroll
                for (int n = 0; n < 4; ++n)
                    acc[m][n] = __builtin_amdgcn_mfma_f32_16x16x32_bf16(
                        a[m], b[n], acc[m][n], 0, 0, 0);
        }
        __syncthreads();
    }

    int lr = (lane >> 4) * 4;
    int lc = lane & 15;
    #pragma unroll
    for (int n = 0; n < 4; ++n) {
        int col = col0 + wc * 64 + n * 16 + lc;
        float bn = bias ? bias[col] : 0.f;
        float en = extra ? extra[col] : 0.f;
        #pragma unroll
        for (int m = 0; m < 4; ++m) {
            int rbase = row0 + wr * 64 + m * 16 + lr;
            #pragma unroll
            for (int r = 0; r < 4; ++r) {
                int row = rbase + r;
                float v = (acc[m][n][r] + bn) * alpha;
                if (flags & FLG_POS) v += pos[(size_t)(row & 511) * N + col];
                v += en;
                if (resid) v += resid[(size_t)row * N + col];
                if (flags & FLG_RELU) v = fmaxf(v, 0.f);
                if (flags & FLG_HEAD) {
                    int bb = row >> 9, ss = row & 511;
                    int hh = col >> 6, dd = col & 63;
                    if (flags & FLG_VT)
                        Cb[((((size_t)bb * NH_ + hh) * HD_ + dd) << 9) + ss] = f2b(v);
                    else
                        Cb[((((size_t)bb * NH_ + hh) * S_ + ss) << 6) + dd] = f2b(v);
                } else if (Cb) {
                    Cb[(size_t)row * N + col] = f2b(v);
                }
                if (Cf) {
                    if (flags & FLG_NT)
                        __builtin_nontemporal_store(v, &Cf[(size_t)row * N + col]);
                    else
                        Cf[(size_t)row * N + col] = v;
                }
            }
        }
    }
}

// ---------------------------------------------------------------------------
// Attention scores (bf16 MFMA): att[bh,q,k] f32, causal kt<=qt only.
// q,k in head-major bf16 [B*NH][S][HD]. grid (8 qt, 32 bh), 256 thr.
// Wave w handles q-rows w*16..w*16+15.
// ---------------------------------------------------------------------------
__global__ __launch_bounds__(256) void att_scores_mfma_kernel(
    const ushort* __restrict__ q, const ushort* __restrict__ k,
    float* __restrict__ att)
{
    int qt = blockIdx.x, bh = blockIdx.y;
    __shared__ ushort Qs[64 * 64];
    __shared__ ushort Ks[64 * 64];
    int t = threadIdx.x, w = t >> 6, lane = t & 63;
    const ushort* Qp = q + ((size_t)bh * S_ + qt * 64) * HD_;   // contiguous 8KB
    gload16(Qp + t * 8, Qs + t * 8);
    gload16(Qp + 2048 + t * 8, Qs + 2048 + t * 8);
    int lr = (lane >> 4) * 4, lc = lane & 15;
    for (int kt = 0; kt <= qt; ++kt) {
        const ushort* Kp = k + ((size_t)bh * S_ + kt * 64) * HD_;
        gload16(Kp + t * 8, Ks + t * 8);
        gload16(Kp + 2048 + t * 8, Ks + 2048 + t * 8);
        __syncthreads();
        const ushort* Ab = Qs + (w * 16 + (lane & 15)) * 64 + (lane >> 4) * 8;
        const ushort* Bb = Ks + ((lane & 15)) * 64 + (lane >> 4) * 8;
        f32x4 sa[4] = {};
        #pragma unroll
        for (int kk = 0; kk < 2; ++kk) {
            bf16x8 av = *reinterpret_cast<const bf16x8*>(Ab + kk * 32);
            #pragma unroll
            for (int n = 0; n < 4; ++n) {
                bf16x8 bv = *reinterpret_cast<const bf16x8*>(Bb + n * 16 * 64 + kk * 32);
                sa[n] = __builtin_amdgcn_mfma_f32_16x16x32_bf16(av, bv, sa[n], 0, 0, 0);
            }
        }
        #pragma unroll
        for (int n = 0; n < 4; ++n) {
            int col = kt * 64 + n * 16 + lc;
            #pragma unroll
            for (int r = 0; r < 4; ++r) {
                int row = qt * 64 + w * 16 + lr + r;
                att[((size_t)bh * S_ + row) * S_ + col] = sa[n][r];
            }
        }
        __syncthreads();
    }
}

// ---------------------------------------------------------------------------
// Softmax f32 att -> bf16 P (zero tail). One wave per (q,bh).
// ---------------------------------------------------------------------------
__global__ __launch_bounds__(64) void softmax_bf16_kernel(
    const float* __restrict__ att, ushort* __restrict__ attb)
{
    int qq = blockIdx.x, bh = blockIdx.y;
    const float* row = att + ((size_t)bh * S_ + qq) * S_;
    ushort* orow = attb + ((size_t)bh * S_ + qq) * S_;
    int t = threadIdx.x;
    int n = qq + 1;
    float m = -1e30f;
    #pragma unroll
    for (int j = 0; j < 8; ++j) {
        int i = t + j * 64;
        if (i < n) m = fmaxf(m, row[i]);
    }
    #pragma unroll
    for (int o = 32; o > 0; o >>= 1) m = fmaxf(m, __shfl_xor(m, o));
    float e[8];
    float sum = 0.f;
    #pragma unroll
    for (int j = 0; j < 8; ++j) {
        int i = t + j * 64;
        float v = (i < n) ? __expf(row[i] - m) : 0.f;
        e[j] = v; sum += v;
    }
    #pragma unroll
    for (int o = 32; o > 0; o >>= 1) sum += __shfl_xor(sum, o);
    float inv = 1.f / sum;
    #pragma unroll
    for (int j = 0; j < 8; ++j)
        orow[t + j * 64] = f2b(e[j] * inv);
}

// ---------------------------------------------------------------------------
// PV (bf16 MFMA): pv[b,s,d] bf16 <- P[bh] @ V[bh], V transposed [bh][d][s].
// grid (8 qt, 32 bh), 256 thr; kt loop <= qt (P tail is zero anyway).
// ---------------------------------------------------------------------------
__global__ __launch_bounds__(256) void att_pv_mfma_kernel(
    const ushort* __restrict__ attb, const ushort* __restrict__ vT,
    ushort* __restrict__ pv)
{
    int qt = blockIdx.x, bh = blockIdx.y;
    __shared__ ushort Ps[64 * 64];
    __shared__ ushort Vs[64 * 64];
    int t = threadIdx.x, w = t >> 6, lane = t & 63;
    const ushort* Pp = attb + ((size_t)bh * S_ + qt * 64) * S_;
    const ushort* Vp = vT + (size_t)bh * HD_ * S_;
    int rr = t >> 3, c8 = (t & 7) * 8;
    f32x4 acc[4] = {};
    for (int kt = 0; kt <= qt; ++kt) {
        gload16(Pp + (size_t)rr * S_ + kt * 64 + c8, Ps + t * 8);
        gload16(Pp + (size_t)(rr + 32) * S_ + kt * 64 + c8, Ps + 2048 + t * 8);
        gload16(Vp + (size_t)rr * S_ + kt * 64 + c8, Vs + t * 8);
        gload16(Vp + (size_t)(rr + 32) * S_ + kt * 64 + c8, Vs + 2048 + t * 8);
        __syncthreads();
        const ushort* Ab = Ps + (w * 16 + (lane & 15)) * 64 + (lane >> 4) * 8;
        const ushort* Bb = Vs + ((lane & 15)) * 64 + (lane >> 4) * 8;
        #pragma unroll
        for (int kk = 0; kk < 2; ++kk) {
            bf16x8 av = *reinterpret_cast<const bf16x8*>(Ab + kk * 32);
            #pragma unroll
            for (int n = 0; n < 4; ++n) {
                bf16x8 bv = *reinterpret_cast<const bf16x8*>(Bb + n * 16 * 64 + kk * 32);
                acc[n] = __builtin_amdgcn_mfma_f32_16x16x32_bf16(av, bv, acc[n], 0, 0, 0);
            }
        }
        __syncthreads();
    }
    int lr = (lane >> 4) * 4, lc = lane & 15;
    int bb = bh >> 2, hh = bh & 3;
    #pragma unroll
    for (int n = 0; n < 4; ++n) {
        int dd = n * 16 + lc;
        #pragma unroll
        for (int r = 0; r < 4; ++r) {
            int ss = qt * 64 + w * 16 + lr + r;
            pv[((size_t)bb * S_ + ss) * D_ + hh * HD_ + dd] = f2b(acc[n][r]);
        }
    }
}

// CA constant: cc[l,:] = ca_bv[l] @ ca_Wo[l] + ca_bo[l]  (exact reduction)
__global__ __launch_bounds__(256) void cc_kernel(
    const float* __restrict__ bv, const float* __restrict__ Wo,
    const float* __restrict__ bo, float* __restrict__ cc)
{
    int l = blockIdx.x;
    int j = threadIdx.x;
    const float* w = Wo + (size_t)l * D_ * D_;
    const float* b = bv + l * D_;
    float acc = 0.f;
    for (int d = 0; d < D_; ++d) acc += b[d] * w[(size_t)d * D_ + j];
    cc[l * D_ + j] = acc + bo[l * D_ + j];
}

// ===========================================================================
// FALLBACK f32 KERNELS (round-0 path, used only if ws is too small)
// ===========================================================================
__global__ __launch_bounds__(256) void embed_scores_kernel(
    const int* __restrict__ tok, const float* __restrict__ table,
    float* __restrict__ scores)
{
    int bs = blockIdx.x;
    int b = bs >> 9, s = bs & 511;
    int j = threadIdx.x;
    float a0 = 0.f, a1 = 0.f;
    #pragma unroll
    for (int c = 0; c < CTX_; ++c) {
        int pos = s + c - (CTX_ - 1);
        int t = (pos < 0) ? 0 : tok[b * S_ + pos];
        const float* row = table + (size_t)t * NC_;
        a0 += row[j];
        a1 += row[j + 256];
    }
    scores[(size_t)bs * NC_ + j]       = a0 * 0.125f;
    scores[(size_t)bs * NC_ + j + 256] = a1 * 0.125f;
}

__global__ __launch_bounds__(256) void ln_kernel(
    const float* __restrict__ x, const float* __restrict__ sc,
    const float* __restrict__ bi, float* __restrict__ out)
{
    __shared__ float red[256];
    int row = blockIdx.x;
    int t = threadIdx.x;
    float v = x[(size_t)row * D_ + t];
    red[t] = v;
    __syncthreads();
    for (int o = 128; o > 0; o >>= 1) { if (t < o) red[t] += red[t + o]; __syncthreads(); }
    float mean = red[0] * (1.f / D_);
    __syncthreads();
    float d = v - mean;
    red[t] = d * d;
    __syncthreads();
    for (int o = 128; o > 0; o >>= 1) { if (t < o) red[t] += red[t + o]; __syncthreads(); }
    float var = red[0] * (1.f / D_);
    float r = rsqrtf(var + 1e-5f);
    out[(size_t)row * D_ + t] = d * r * sc[t] + bi[t];
}

__global__ __launch_bounds__(256) void gemm_kernel(
    const float* __restrict__ A, const float* __restrict__ B,
    const float* __restrict__ bias, const float* __restrict__ extra,
    const float* __restrict__ resid, const float* __restrict__ pos,
    float* __restrict__ C, int M, int N, int K, float alpha, int flags)
{
    __shared__ float As[64][68];
    __shared__ float Bs[64][68];
    int col0 = blockIdx.x * 64;
    int row0 = blockIdx.y * 64;
    int t = threadIdx.x;
    int tx = t & 15, ty = t >> 4;
    int lc = (t & 15) * 4;
    int lr = t >> 4;
    float acc[4][4] = {};
    for (int k0 = 0; k0 < K; k0 += 64) {
        #pragma unroll
        for (int p = 0; p < 4; ++p) {
            int r = lr + p * 16;
            *reinterpret_cast<float4*>(&As[r][lc]) =
                *reinterpret_cast<const float4*>(&A[(size_t)(row0 + r) * K + k0 + lc]);
            *reinterpret_cast<float4*>(&Bs[r][lc]) =
                *reinterpret_cast<const float4*>(&B[(size_t)(k0 + r) * N + col0 + lc]);
        }
        __syncthreads();
        #pragma unroll 8
        for (int kk = 0; kk < 64; ++kk) {
            float4 b4 = *reinterpret_cast<const float4*>(&Bs[kk][tx * 4]);
            float a0 = As[ty * 4 + 0][kk];
            float a1 = As[ty * 4 + 1][kk];
            float a2 = As[ty * 4 + 2][kk];
            float a3 = As[ty * 4 + 3][kk];
            acc[0][0] += a0 * b4.x; acc[0][1] += a0 * b4.y; acc[0][2] += a0 * b4.z; acc[0][3] += a0 * b4.w;
            acc[1][0] += a1 * b4.x; acc[1][1] += a1 * b4.y; acc[1][2] += a1 * b4.z; acc[1][3] += a1 * b4.w;
            acc[2][0] += a2 * b4.x; acc[2][1] += a2 * b4.y; acc[2][2] += a2 * b4.z; acc[2][3] += a2 * b4.w;
            acc[3][0] += a3 * b4.x; acc[3][1] += a3 * b4.y; acc[3][2] += a3 * b4.z; acc[3][3] += a3 * b4.w;
        }
        __syncthreads();
    }
    #pragma unroll
    for (int i = 0; i < 4; ++i) {
        int row = row0 + ty * 4 + i;
        #pragma unroll
        for (int j = 0; j < 4; ++j) {
            int col = col0 + tx * 4 + j;
            float v = acc[i][j];
            if (bias) v += bias[col];
            v *= alpha;
            if (flags & 4) v += pos[(size_t)(row & 511) * N + col];
            if (extra) v += extra[col];
            if (resid) v += resid[(size_t)row * N + col];
            if (flags & 1) v = fmaxf(v, 0.f);
            if (flags & 2) {
                int bb = row >> 9, ss = row & 511;
                int hh = col >> 6, dd = col & 63;
                C[((((size_t)bb * NH_ + hh) * S_ + ss) << 6) + dd] = v;
            } else {
                C[(size_t)row * N + col] = v;
            }
        }
    }
}

__global__ __launch_bounds__(256) void att_scores_kernel(
    const float* __restrict__ q, const float* __restrict__ k,
    float* __restrict__ att)
{
    int kt = blockIdx.x, qt = blockIdx.y, bh = blockIdx.z;
    if (kt > qt) return;
    __shared__ float Qs[64][68];
    __shared__ float Ks[64][68];
    const float* Qp = q + ((size_t)bh * S_ + qt * 64) * HD_;
    const float* Kp = k + ((size_t)bh * S_ + kt * 64) * HD_;
    int t = threadIdx.x, tx = t & 15, ty = t >> 4;
    int lc = (t & 15) * 4, lr = t >> 4;
    #pragma unroll
    for (int p = 0; p < 4; ++p) {
        int r = lr + p * 16;
        *reinterpret_cast<float4*>(&Qs[r][lc]) =
            *reinterpret_cast<const float4*>(&Qp[r * HD_ + lc]);
        *reinterpret_cast<float4*>(&Ks[r][lc]) =
            *reinterpret_cast<const float4*>(&Kp[r * HD_ + lc]);
    }
    __syncthreads();
    float acc[4][4] = {};
    #pragma unroll 8
    for (int d = 0; d < 64; ++d) {
        float qv[4], kv[4];
        #pragma unroll
        for (int i = 0; i < 4; ++i) qv[i] = Qs[ty * 4 + i][d];
        #pragma unroll
        for (int j = 0; j < 4; ++j) kv[j] = Ks[tx * 4 + j][d];
        #pragma unroll
        for (int i = 0; i < 4; ++i)
            #pragma unroll
            for (int j = 0; j < 4; ++j)
                acc[i][j] += qv[i] * kv[j];
    }
    #pragma unroll
    for (int i = 0; i < 4; ++i) {
        int qq = qt * 64 + ty * 4 + i;
        #pragma unroll
        for (int j = 0; j < 4; ++j) {
            int kk = kt * 64 + tx * 4 + j;
            att[((size_t)bh * S_ + qq) * S_ + kk] = acc[i][j];
        }
    }
}

__global__ __launch_bounds__(64) void softmax_kernel(float* __restrict__ att)
{
    int qq = blockIdx.x;
    int bh = blockIdx.y;
    float* row = att + ((size_t)bh * S_ + qq) * S_;
    int t = threadIdx.x;
    int n = qq + 1;
    float m = -1e30f;
    for (int i = t; i < n; i += 64) m = fmaxf(m, row[i]);
    #pragma unroll
    for (int o = 32; o > 0; o >>= 1) m = fmaxf(m, __shfl_xor(m, o));
    float sum = 0.f;
    for (int i = t; i < n; i += 64) { float e = __expf(row[i] - m); row[i] = e; sum += e; }
    #pragma unroll
    for (int o = 32; o > 0; o >>= 1) sum += __shfl_xor(sum, o);
    float inv = 1.f / sum;
    for (int i = t; i < S_; i += 64) row[i] = (i < n) ? row[i] * inv : 0.f;
}

__global__ __launch_bounds__(256) void att_pv_kernel(
    const float* __restrict__ att, const float* __restrict__ v,
    float* __restrict__ out)
{
    int rt = blockIdx.x;
    int bh = blockIdx.y;
    __shared__ float As2[64][68];
    __shared__ float Bs2[64][68];
    const float* Ap = att + ((size_t)bh * S_ + rt * 64) * S_;
    const float* Vp = v + (size_t)bh * S_ * HD_;
    int t = threadIdx.x, tx = t & 15, ty = t >> 4;
    int lc = (t & 15) * 4, lr = t >> 4;
    float acc[4][4] = {};
    for (int k0 = 0; k0 < S_; k0 += 64) {
        #pragma unroll
        for (int p = 0; p < 4; ++p) {
            int r = lr + p * 16;
            *reinterpret_cast<float4*>(&As2[r][lc]) =
                *reinterpret_cast<const float4*>(&Ap[(size_t)r * S_ + k0 + lc]);
            *reinterpret_cast<float4*>(&Bs2[r][lc]) =
                *reinterpret_cast<const float4*>(&Vp[(size_t)(k0 + r) * HD_ + lc]);
        }
        __syncthreads();
        #pragma unroll 8
        for (int kk = 0; kk < 64; ++kk) {
            float4 b4 = *reinterpret_cast<const float4*>(&Bs2[kk][tx * 4]);
            float a0 = As2[ty * 4 + 0][kk];
            float a1 = As2[ty * 4 + 1][kk];
            float a2 = As2[ty * 4 + 2][kk];
            float a3 = As2[ty * 4 + 3][kk];
            acc[0][0] += a0 * b4.x; acc[0][1] += a0 * b4.y; acc[0][2] += a0 * b4.z; acc[0][3] += a0 * b4.w;
            acc[1][0] += a1 * b4.x; acc[1][1] += a1 * b4.y; acc[1][2] += a1 * b4.z; acc[1][3] += a1 * b4.w;
            acc[2][0] += a2 * b4.x; acc[2][1] += a2 * b4.y; acc[2][2] += a2 * b4.z; acc[2][3] += a2 * b4.w;
            acc[3][0] += a3 * b4.x; acc[3][1] += a3 * b4.y; acc[3][2] += a3 * b4.z; acc[3][3] += a3 * b4.w;
        }
        __syncthreads();
    }
    int bb = bh >> 2, hh = bh & 3;
    #pragma unroll
    for (int i = 0; i < 4; ++i) {
        int ss = rt * 64 + ty * 4 + i;
        #pragma unroll
        for (int j = 0; j < 4; ++j) {
            int dd = tx * 4 + j;
            out[((size_t)bb * S_ + ss) * D_ + hh * HD_ + dd] = acc[i][j];
        }
    }
}

// ===========================================================================
extern "C" void kernel_launch(void* const* d_in, const int* in_sizes, int n_in,
                              void* d_out, int out_size, void* d_ws, size_t ws_size,
                              hipStream_t stream)
{
    const int*   tok     = (const int*)  d_in[0];
    const float* ram     = (const float*)d_in[1];
    const float* proj_W  = (const float*)d_in[2];
    const float* proj_b  = (const float*)d_in[3];
    const float* pos_emb = (const float*)d_in[4];
    const float* sa_Wq   = (const float*)d_in[5];
    const float* sa_Wk   = (const float*)d_in[6];
    const float* sa_Wv   = (const float*)d_in[7];
    const float* sa_Wo   = (const float*)d_in[8];
    const float* sa_bq   = (const float*)d_in[9];
    const float* sa_bk   = (const float*)d_in[10];
    const float* sa_bv   = (const float*)d_in[11];
    const float* sa_bo   = (const float*)d_in[12];
    const float* ca_Wo   = (const float*)d_in[16];
    const float* ca_bv   = (const float*)d_in[19];
    const float* ca_bo   = (const float*)d_in[20];
    const float* ln1_s   = (const float*)d_in[21];
    const float* ln1_b   = (const float*)d_in[22];
    const float* ln3_s   = (const float*)d_in[25];
    const float* ln3_b   = (const float*)d_in[26];
    const float* ff_W1   = (const float*)d_in[27];
    const float* ff_b1   = (const float*)d_in[28];
    const float* ff_W2   = (const float*)d_in[29];
    const float* ff_b2   = (const float*)d_in[30];
    const float* out_W   = (const float*)d_in[31];
    const float* out_b   = (const float*)d_in[32];

    float* out = (float*)d_out;
    float* ws  = (float*)d_ws;

    // ws layout (must survive until the logits GEMM): x | cc | xb | Wb_out
    float*  x   = ws;
    float*  cc  = ws + (size_t)BS_ * D_;
    ushort* xb  = (ushort*)(cc + L_ * D_);
    ushort* Wb  = xb + (size_t)BS_ * D_;
    size_t need = ((size_t)BS_ * D_ + L_ * D_) * 4 +
                  (size_t)BS_ * D_ * 2 + (size_t)V_ * D_ * 2;
    bool fast = (ws_size >= need);

    if (fast) {
        // d_out scratch (fully overwritten by the final logits GEMM)
        float*  att   = out;                          // 8,388,608 f32
        ushort* sc_b  = (ushort*)(out + 8388608);     // 2,097,152
        ushort* h_b   = sc_b + 2097152;               // 1,048,576
        ushort* qb_b  = h_b  + 1048576;
        ushort* kb_b  = qb_b + 1048576;
        ushort* vT_b  = kb_b + 1048576;
        ushort* pv_b  = vT_b + 1048576;
        ushort* attb  = pv_b + 1048576;               // 8,388,608
        ushort* ffh_b = attb + 8388608;               // 2,097,152
        ushort* pjWb  = ffh_b + 2097152;              // 131,072
        ushort* WqB   = pjWb + 131072;                // 262,144 (L*D*D)
        ushort* WkB   = WqB + 262144;
        ushort* WvB   = WkB + 262144;
        ushort* WoB   = WvB + 262144;
        ushort* ff1B  = WoB + 262144;                 // 524,288
        ushort* ff2B  = ff1B + 524288;                // 524,288

        cc_kernel<<<L_, 256, 0, stream>>>(ca_bv, ca_Wo, ca_bo, cc);
        embed_bf16_kernel<<<BS_, 256, 0, stream>>>(tok, ram, sc_b);

        dim3 tb(32, 8);
        transpose_bf16_kernel<<<dim3(D_ / 32, NC_ / 32, 1), tb, 0, stream>>>(proj_W, pjWb, NC_, D_);
        transpose_bf16_kernel<<<dim3(D_ / 32, D_ / 32, L_), tb, 0, stream>>>(sa_Wq, WqB, D_, D_);
        transpose_bf16_kernel<<<dim3(D_ / 32, D_ / 32, L_), tb, 0, stream>>>(sa_Wk, WkB, D_, D_);
        transpose_bf16_kernel<<<dim3(D_ / 32, D_ / 32, L_), tb, 0, stream>>>(sa_Wv, WvB, D_, D_);
        transpose_bf16_kernel<<<dim3(D_ / 32, D_ / 32, L_), tb, 0, stream>>>(sa_Wo, WoB, D_, D_);
        transpose_bf16_kernel<<<dim3(FF_ / 32, D_ / 32, L_), tb, 0, stream>>>(ff_W1, ff1B, D_, FF_);
        transpose_bf16_kernel<<<dim3(D_ / 32, FF_ / 32, L_), tb, 0, stream>>>(ff_W2, ff2B, FF_, D_);
        transpose_bf16_kernel<<<dim3(V_ / 32, D_ / 32, 1), tb, 0, stream>>>(out_W, Wb, D_, V_);

        // x = scores @ proj_W + proj_b + pos_emb
        mfma_gemm_kernel<<<32 * (D_ / 128), 256, 0, stream>>>(
            sc_b, pjWb, proj_b, nullptr, nullptr, pos_emb, x, nullptr,
            D_, NC_, 1.f, FLG_POS);

        for (int l = 0; l < L_; ++l) {
            ln_bf16_kernel<<<BS_, 256, 0, stream>>>(x, ln1_s + l * D_, ln1_b + l * D_, h_b);
            mfma_gemm_kernel<<<32 * (D_ / 128), 256, 0, stream>>>(
                h_b, WqB + (size_t)l * D_ * D_, sa_bq + l * D_, nullptr, nullptr, nullptr,
                nullptr, qb_b, D_, D_, 0.125f, FLG_HEAD);
            mfma_gemm_kernel<<<32 * (D_ / 128), 256, 0, stream>>>(
                h_b, WkB + (size_t)l * D_ * D_, sa_bk + l * D_, nullptr, nullptr, nullptr,
                nullptr, kb_b, D_, D_, 1.f, FLG_HEAD);
            mfma_gemm_kernel<<<32 * (D_ / 128), 256, 0, stream>>>(
                h_b, WvB + (size_t)l * D_ * D_, sa_bv + l * D_, nullptr, nullptr, nullptr,
                nullptr, vT_b, D_, D_, 1.f, FLG_HEAD | FLG_VT);

            att_scores_mfma_kernel<<<dim3(8, 32), 256, 0, stream>>>(qb_b, kb_b, att);
            softmax_bf16_kernel<<<dim3(S_, 32), 64, 0, stream>>>(att, attb);
            att_pv_mfma_kernel<<<dim3(8, 32), 256, 0, stream>>>(attb, vT_b, pv_b);

            mfma_gemm_kernel<<<32 * (D_ / 128), 256, 0, stream>>>(
                pv_b, WoB + (size_t)l * D_ * D_, sa_bo + l * D_, cc + l * D_, x, nullptr,
                x, nullptr, D_, D_, 1.f, 0);

            ln_bf16_kernel<<<BS_, 256, 0, stream>>>(x, ln3_s + l * D_, ln3_b + l * D_, h_b);
            mfma_gemm_kernel<<<32 * (FF_ / 128), 256, 0, stream>>>(
                h_b, ff1B + (size_t)l * D_ * FF_, ff_b1 + l * FF_, nullptr, nullptr, nullptr,
                nullptr, ffh_b, FF_, D_, 1.f, FLG_RELU);
            mfma_gemm_kernel<<<32 * (D_ / 128), 256, 0, stream>>>(
                ffh_b, ff2B + (size_t)l * FF_ * D_, ff_b2 + l * D_, nullptr, x, nullptr,
                x, nullptr, D_, FF_, 1.f, 0);
        }

        f32_to_bf16_kernel<<<(BS_ * D_ / 4 + 255) / 256, 256, 0, stream>>>(x, xb, BS_ * D_ / 4);
        mfma_gemm_kernel<<<32 * (V_ / 128), 256, 0, stream>>>(
            xb, Wb, out_b, nullptr, nullptr, nullptr, out, nullptr,
            V_, D_, 1.f, FLG_NT);
    } else {
        // full f32 fallback (round-0 path)
        float* att  = out;
        float* h    = out + (size_t)8 * 1024 * 1024;
        float* qb   = h   + (size_t)BS_ * D_;
        float* kb   = qb  + (size_t)BS_ * D_;
        float* vb   = kb  + (size_t)BS_ * D_;
        float* pv   = vb  + (size_t)BS_ * D_;
        float* tbuf = pv  + (size_t)BS_ * D_;

        cc_kernel<<<L_, 256, 0, stream>>>(ca_bv, ca_Wo, ca_bo, cc);
        embed_scores_kernel<<<BS_, 256, 0, stream>>>(tok, ram, tbuf);
        gemm_kernel<<<dim3(D_ / 64, BS_ / 64), 256, 0, stream>>>(
            tbuf, proj_W, proj_b, nullptr, nullptr, pos_emb, x, BS_, D_, NC_, 1.f, 4);
        for (int l = 0; l < L_; ++l) {
            const float* Wq = sa_Wq + (size_t)l * D_ * D_;
            const float* Wk = sa_Wk + (size_t)l * D_ * D_;
            const float* Wv = sa_Wv + (size_t)l * D_ * D_;
            const float* Wo = sa_Wo + (size_t)l * D_ * D_;
            ln_kernel<<<BS_, 256, 0, stream>>>(x, ln1_s + l * D_, ln1_b + l * D_, h);
            gemm_kernel<<<dim3(D_ / 64, BS_ / 64), 256, 0, stream>>>(
                h, Wq, sa_bq + l * D_, nullptr, nullptr, nullptr, qb, BS_, D_, D_, 0.125f, 2);
            gemm_kernel<<<dim3(D_ / 64, BS_ / 64), 256, 0, stream>>>(
                h, Wk, sa_bk + l * D_, nullptr, nullptr, nullptr, kb, BS_, D_, D_, 1.f, 2);
            gemm_kernel<<<dim3(D_ / 64, BS_ / 64), 256, 0, stream>>>(
                h, Wv, sa_bv + l * D_, nullptr, nullptr, nullptr, vb, BS_, D_, D_, 1.f, 2);
            att_scores_kernel<<<dim3(8, 8, 32), 256, 0, stream>>>(qb, kb, att);
            softmax_kernel<<<dim3(S_, 32), 64, 0, stream>>>(att);
            att_pv_kernel<<<dim3(8, 32), 256, 0, stream>>>(att, vb, pv);
            gemm_kernel<<<dim3(D_ / 64, BS_ / 64), 256, 0, stream>>>(
                pv, Wo, sa_bo + l * D_, cc + l * D_, x, nullptr, x, BS_, D_, D_, 1.f, 0);
            ln_kernel<<<BS_, 256, 0, stream>>>(x, ln3_s + l * D_, ln3_b + l * D_, h);
            gemm_kernel<<<dim3(FF_ / 64, BS_ / 64), 256, 0, stream>>>(
                h, ff_W1 + (size_t)l * D_ * FF_, ff_b1 + l * FF_, nullptr, nullptr, nullptr,
                tbuf, BS_, FF_, D_, 1.f, 1);
            gemm_kernel<<<dim3(D_ / 64, BS_ / 64), 256, 0, stream>>>(
                tbuf, ff_W2 + (size_t)l * FF_ * D_, ff_b2 + l * D_, nullptr, x, nullptr,
                x, BS_, D_, FF_, 1.f, 0);
        }
        gemm_kernel<<<dim3(V_ / 64, BS_ / 64), 256, 0, stream>>>(
            x, out_W, out_b, nullptr, nullptr, nullptr, out, BS_, V_, D_, 1.f, 0);
    }
}

// Round 4
// 478.544 us; speedup vs baseline: 2.2059x; 2.2059x over previous
//
#include <hip/hip_runtime.h>

#define B_   8
#define S_   512
#define V_   32000
#define CTX_ 8
#define NC_  512
#define D_   256
#define NH_  4
#define L_   4
#define FF_  512
#define HD_  64
#define BS_  4096   // B_*S_

#define FG_F32  1   // write Cf f32 [row][TN]
#define FG_BF16 2   // write Cb bf16 [row][TN]
#define FG_RELU 4
#define FG_POS  8
#define FG_NT   16
#define FG_QKV  32  // route to q/k/vT head layouts (TN=768)

typedef __attribute__((ext_vector_type(8))) short bf16x8;
typedef __attribute__((ext_vector_type(4))) float f32x4;

__device__ inline void gload16(const void* g, void* lds) {
    __builtin_amdgcn_global_load_lds(
        (const __attribute__((address_space(1))) void*)g,
        (__attribute__((address_space(3))) void*)lds, 16, 0, 0);
}

__device__ inline ushort f2b(float f) {   // f32 -> bf16 RNE
    union { float f; unsigned u; } v; v.f = f;
    unsigned u = v.u;
    unsigned r = u + 0x7fffu + ((u >> 16) & 1u);
    return (ushort)(r >> 16);
}

// ---------------------------------------------------------------------------
// Embedding: bf16 scores [BS][NC], pre-scaled by 1/8 (window mean)
// ---------------------------------------------------------------------------
__global__ __launch_bounds__(256) void embed_bf16_kernel(
    const int* __restrict__ tok, const float* __restrict__ table,
    ushort* __restrict__ scores)
{
    int bs = blockIdx.x;
    int b = bs >> 9, s = bs & 511;
    int j = threadIdx.x;
    float a0 = 0.f, a1 = 0.f;
    #pragma unroll
    for (int c = 0; c < CTX_; ++c) {
        int pos = s + c - (CTX_ - 1);
        int t = (pos < 0) ? 0 : tok[b * S_ + pos];
        const float* row = table + (size_t)t * NC_;
        a0 += row[j];
        a1 += row[j + 256];
    }
    scores[(size_t)bs * NC_ + j]       = f2b(a0 * 0.125f);
    scores[(size_t)bs * NC_ + j + 256] = f2b(a1 * 0.125f);
}

// ---------------------------------------------------------------------------
// LayerNorm f32 -> bf16, one WAVE per row (4 rows / 256-thread block)
// ---------------------------------------------------------------------------
__global__ __launch_bounds__(256) void ln_bf16_kernel(
    const float* __restrict__ x, const float* __restrict__ sc,
    const float* __restrict__ bi, ushort* __restrict__ out)
{
    int row = blockIdx.x * 4 + (threadIdx.x >> 6);
    int lane = threadIdx.x & 63;
    float4 v = *reinterpret_cast<const float4*>(x + (size_t)row * D_ + lane * 4);
    float s = v.x + v.y + v.z + v.w;
    float s2 = v.x * v.x + v.y * v.y + v.z * v.z + v.w * v.w;
    #pragma unroll
    for (int o = 32; o > 0; o >>= 1) {
        s  += __shfl_xor(s, o);
        s2 += __shfl_xor(s2, o);
    }
    float mean = s * (1.f / D_);
    float var = s2 * (1.f / D_) - mean * mean;
    float r = rsqrtf(var + 1e-5f);
    float4 g = *reinterpret_cast<const float4*>(sc + lane * 4);
    float4 bb = *reinterpret_cast<const float4*>(bi + lane * 4);
    ushort4 o4;
    o4.x = f2b((v.x - mean) * r * g.x + bb.x);
    o4.y = f2b((v.y - mean) * r * g.y + bb.y);
    o4.z = f2b((v.z - mean) * r * g.z + bb.z);
    o4.w = f2b((v.w - mean) * r * g.w + bb.w);
    *reinterpret_cast<ushort4*>(out + (size_t)row * D_ + lane * 4) = o4;
}

// ---------------------------------------------------------------------------
// Generic transpose+convert: W[K][N] f32 (layer z) -> Wb[N][K] bf16
// ---------------------------------------------------------------------------
__global__ void transpose_bf16_kernel(const float* __restrict__ W,
                                      ushort* __restrict__ Wb, int K, int N)
{
    int l = blockIdx.z;
    W  += (size_t)l * K * N;
    Wb += (size_t)l * K * N;
    __shared__ float tile[32][33];
    int n0 = blockIdx.x * 32, k0 = blockIdx.y * 32;
    for (int i = threadIdx.y; i < 32; i += 8)
        tile[i][threadIdx.x] = W[(size_t)(k0 + i) * N + n0 + threadIdx.x];
    __syncthreads();
    for (int i = threadIdx.y; i < 32; i += 8)
        Wb[(size_t)(n0 + i) * K + k0 + threadIdx.x] = f2b(tile[threadIdx.x][i]);
}

// QKV concat transpose: dst[l][768][256] bf16; z = which*L + l
__global__ void transpose_qkv_kernel(const float* __restrict__ Wq,
                                     const float* __restrict__ Wk,
                                     const float* __restrict__ Wv,
                                     ushort* __restrict__ dst)
{
    int z = blockIdx.z;
    int which = z / L_, l = z % L_;
    const float* W = (which == 0 ? Wq : which == 1 ? Wk : Wv) + (size_t)l * D_ * D_;
    ushort* Wb = dst + ((size_t)l * 768 + which * 256) * 256;
    __shared__ float tile[32][33];
    int n0 = blockIdx.x * 32, k0 = blockIdx.y * 32;
    for (int i = threadIdx.y; i < 32; i += 8)
        tile[i][threadIdx.x] = W[(size_t)(k0 + i) * D_ + n0 + threadIdx.x];
    __syncthreads();
    for (int i = threadIdx.y; i < 32; i += 8)
        Wb[(size_t)(n0 + i) * D_ + k0 + threadIdx.x] = f2b(tile[threadIdx.x][i]);
}

// pack qkv bias [L][768]
__global__ void pack_qkv_bias_kernel(const float* __restrict__ bq,
                                     const float* __restrict__ bk,
                                     const float* __restrict__ bv,
                                     float* __restrict__ out)
{
    int l = blockIdx.x, t = threadIdx.x;
    int which = t >> 8, c = t & 255;
    const float* src = which == 0 ? bq : which == 1 ? bk : bv;
    out[l * 768 + t] = src[l * 256 + c];
}

// CA constant: cc[l,:] = ca_bv[l] @ ca_Wo[l] + ca_bo[l]  (exact reduction)
__global__ __launch_bounds__(256) void cc_kernel(
    const float* __restrict__ bv, const float* __restrict__ Wo,
    const float* __restrict__ bo, float* __restrict__ cc)
{
    int l = blockIdx.x;
    int j = threadIdx.x;
    const float* w = Wo + (size_t)l * D_ * D_;
    const float* b = bv + l * D_;
    float acc = 0.f;
    for (int d = 0; d < D_; ++d) acc += b[d] * w[(size_t)d * D_ + j];
    cc[l * D_ + j] = acc + bo[l * D_ + j];
}

// ---------------------------------------------------------------------------
// Templated bf16 MFMA GEMM.  A[4096][K] bf16, Bt[TN][K] bf16.
// 4 waves (2x2).  BK=64.  LDS XOR-swizzled (T2, both-sides rule #21):
// stage with global col-slot (slot^srow), read with slot^(row&7).
// ---------------------------------------------------------------------------
template<int BM, int BN, int K, int TN, int FLAGS>
__global__ __launch_bounds__(256) void gemm_t(
    const ushort* __restrict__ A, const ushort* __restrict__ Bt,
    const float* __restrict__ bias, const float* __restrict__ extra,
    const float* __restrict__ resid, const float* __restrict__ pos,
    float* __restrict__ Cf, ushort* __restrict__ Cb)
{
    constexpr int WM = BM / 32;            // a-frags per wave
    constexpr int WN = BN / 32;
    constexpr int MT = 4096 / BM;
    constexpr int NWG = MT * (TN / BN);
    __shared__ ushort As[BM * 64];
    __shared__ ushort Bs[BN * 64];
    int bid = blockIdx.x;
    int swz = bid;
    if constexpr ((NWG & 7) == 0) {
        constexpr int cpx = NWG >> 3;
        swz = (bid & 7) * cpx + (bid >> 3);
    }
    int mt = swz % MT, nt = swz / MT;
    int row0 = mt * BM, col0 = nt * BN;
    int t = threadIdx.x, w = t >> 6, lane = t & 63;
    int wr = w >> 1, wc = w & 1;
    int srow = lane >> 3, slot = lane & 7;
    int gcol = (slot ^ srow) * 8;          // inverse-swizzled global col

    f32x4 acc[WM][WN] = {};
    int sl = lane >> 4;
    int rA0 = wr * (BM / 2) + (lane & 15);
    int rB0 = wc * (BN / 2) + (lane & 15);

    #pragma unroll
    for (int k0 = 0; k0 < K; k0 += 64) {
        #pragma unroll
        for (int c = 0; c < BM / 32; ++c) {
            int chunk = w * (BM / 32) + c;
            gload16(A + (size_t)(row0 + chunk * 8 + srow) * K + k0 + gcol,
                    As + chunk * 512);
        }
        #pragma unroll
        for (int c = 0; c < BN / 32; ++c) {
            int chunk = w * (BN / 32) + c;
            gload16(Bt + (size_t)(col0 + chunk * 8 + srow) * K + k0 + gcol,
                    Bs + chunk * 512);
        }
        __syncthreads();
        #pragma unroll
        for (int kk = 0; kk < 2; ++kk) {
            bf16x8 a[WM], b[WN];
            #pragma unroll
            for (int m = 0; m < WM; ++m) {
                int rr = rA0 + m * 16;
                a[m] = *reinterpret_cast<const bf16x8*>(
                    As + rr * 64 + (((sl + kk * 4) ^ (rr & 7)) * 8));
            }
            #pragma unroll
            for (int n = 0; n < WN; ++n) {
                int rr = rB0 + n * 16;
                b[n] = *reinterpret_cast<const bf16x8*>(
                    Bs + rr * 64 + (((sl + kk * 4) ^ (rr & 7)) * 8));
            }
            #pragma unroll
            for (int m = 0; m < WM; ++m)
                #pragma unroll
                for (int n = 0; n < WN; ++n)
                    acc[m][n] = __builtin_amdgcn_mfma_f32_16x16x32_bf16(
                        a[m], b[n], acc[m][n], 0, 0, 0);
        }
        __syncthreads();
    }

    int lr = (lane >> 4) * 4;
    int lc = lane & 15;
    #pragma unroll
    for (int n = 0; n < WN; ++n) {
        int col = col0 + wc * (BN / 2) + n * 16 + lc;
        float bn = bias ? bias[col] : 0.f;
        float en = extra ? extra[col] : 0.f;
        #pragma unroll
        for (int m = 0; m < WM; ++m) {
            int rbase = row0 + wr * (BM / 2) + m * 16 + lr;
            #pragma unroll
            for (int r = 0; r < 4; ++r) {
                int row = rbase + r;
                float v = acc[m][n][r] + bn;
                if constexpr (FLAGS & FG_QKV) {
                    int which = col >> 8;
                    int c2 = col & 255;
                    int hh = c2 >> 6, dd = c2 & 63;
                    int bb = row >> 9, ss = row & 511;
                    if (which == 0) {
                        Cb[((((size_t)bb * NH_ + hh) * S_ + ss) << 6) + dd] =
                            f2b(v * 0.125f);
                    } else if (which == 1) {
                        (Cb + 1048576)[((((size_t)bb * NH_ + hh) * S_ + ss) << 6) + dd] =
                            f2b(v);
                    } else {
                        (Cb + 2097152)[((((size_t)bb * NH_ + hh) * HD_ + dd) << 9) + ss] =
                            f2b(v);
                    }
                } else {
                    if constexpr (FLAGS & FG_POS) v += pos[(size_t)(row & 511) * TN + col];
                    if (extra) v += en;
                    if (resid) v += resid[(size_t)row * TN + col];
                    if constexpr (FLAGS & FG_RELU) v = fmaxf(v, 0.f);
                    if constexpr (FLAGS & FG_BF16)
                        Cb[(size_t)row * TN + col] = f2b(v);
                    if constexpr (FLAGS & FG_F32) {
                        if constexpr (FLAGS & FG_NT)
                            __builtin_nontemporal_store(v, &Cf[(size_t)row * TN + col]);
                        else
                            Cf[(size_t)row * TN + col] = v;
                    }
                }
            }
        }
    }
}

// ---------------------------------------------------------------------------
// Fused flash attention: one block per (q-tile, bh).  4 waves x 16 q-rows.
// q,k head-major [bh][s][64] bf16 (q pre-scaled 1/8); v transposed [bh][d][s].
// Online softmax in registers; P via per-wave swizzled LDS; out bf16 [b][s][256].
// ---------------------------------------------------------------------------
__global__ __launch_bounds__(256) void attn_kernel(
    const ushort* __restrict__ q, const ushort* __restrict__ k,
    const ushort* __restrict__ vT, ushort* __restrict__ pv)
{
    int qt = blockIdx.x, bh = blockIdx.y;
    __shared__ ushort Ks[64 * 64];
    __shared__ ushort Vs[64 * 64];
    __shared__ ushort Ps[4 * 16 * 64];
    int t = threadIdx.x, w = t >> 6, lane = t & 63;
    int srow = lane >> 3, slot = lane & 7;
    int gcol = (slot ^ srow) * 8;
    int sl = lane >> 4, lc = lane & 15;

    const ushort* Qp = q + ((size_t)bh * S_ + qt * 64) * HD_;
    const ushort* Kp = k + (size_t)bh * S_ * HD_;
    const ushort* Vp = vT + (size_t)bh * HD_ * S_;

    int qrow = w * 16 + lc;
    bf16x8 qf0 = *reinterpret_cast<const bf16x8*>(Qp + qrow * 64 + sl * 8);
    bf16x8 qf1 = *reinterpret_cast<const bf16x8*>(Qp + qrow * 64 + sl * 8 + 32);

    f32x4 o[4] = {};
    float m_r[4], l_r[4];
    #pragma unroll
    for (int r = 0; r < 4; ++r) { m_r[r] = -1e30f; l_r[r] = 0.f; }
    int row_abs = qt * 64 + w * 16 + sl * 4;

    for (int kt = 0; kt <= qt; ++kt) {
        #pragma unroll
        for (int c = 0; c < 2; ++c) {
            int chunk = w * 2 + c;
            gload16(Kp + (size_t)(kt * 64 + chunk * 8 + srow) * 64 + gcol,
                    Ks + chunk * 512);
            gload16(Vp + (size_t)(chunk * 8 + srow) * 512 + kt * 64 + gcol,
                    Vs + chunk * 512);
        }
        __syncthreads();

        f32x4 sa[4] = {};
        #pragma unroll
        for (int n = 0; n < 4; ++n) {
            int rB = n * 16 + lc;
            bf16x8 b0 = *reinterpret_cast<const bf16x8*>(
                Ks + rB * 64 + ((sl ^ (rB & 7)) * 8));
            bf16x8 b1 = *reinterpret_cast<const bf16x8*>(
                Ks + rB * 64 + (((sl + 4) ^ (rB & 7)) * 8));
            sa[n] = __builtin_amdgcn_mfma_f32_16x16x32_bf16(qf0, b0, sa[n], 0, 0, 0);
            sa[n] = __builtin_amdgcn_mfma_f32_16x16x32_bf16(qf1, b1, sa[n], 0, 0, 0);
        }
        if (kt == qt) {
            #pragma unroll
            for (int n = 0; n < 4; ++n) {
                int col = kt * 64 + n * 16 + lc;
                #pragma unroll
                for (int r = 0; r < 4; ++r)
                    if (col > row_abs + r) sa[n][r] = -1e30f;
            }
        }
        // online softmax: row groups are the 16 lanes sharing (lane>>4)
        float psum[4];
        #pragma unroll
        for (int r = 0; r < 4; ++r) {
            float vm = fmaxf(fmaxf(sa[0][r], sa[1][r]), fmaxf(sa[2][r], sa[3][r]));
            vm = fmaxf(vm, __shfl_xor(vm, 1));
            vm = fmaxf(vm, __shfl_xor(vm, 2));
            vm = fmaxf(vm, __shfl_xor(vm, 4));
            vm = fmaxf(vm, __shfl_xor(vm, 8));
            float mn = fmaxf(m_r[r], vm);
            float scl = __expf(m_r[r] - mn);
            m_r[r] = mn;
            l_r[r] *= scl;
            #pragma unroll
            for (int n = 0; n < 4; ++n) o[n][r] *= scl;
            psum[r] = 0.f;
        }
        ushort* Pw = Ps + w * 1024;
        #pragma unroll
        for (int n = 0; n < 4; ++n) {
            #pragma unroll
            for (int r = 0; r < 4; ++r) {
                float p = __expf(sa[n][r] - m_r[r]);
                psum[r] += p;
                int prow = sl * 4 + r;
                int pcol = n * 16 + lc;
                int pslot = pcol >> 3;
                Pw[prow * 64 + ((pslot ^ (prow & 7)) * 8) + (pcol & 7)] = f2b(p);
            }
        }
        #pragma unroll
        for (int r = 0; r < 4; ++r) {
            float s = psum[r];
            s += __shfl_xor(s, 1);
            s += __shfl_xor(s, 2);
            s += __shfl_xor(s, 4);
            s += __shfl_xor(s, 8);
            l_r[r] += s;
        }
        // P (wave-private LDS) -> A-frags; PV accumulate
        int arow = lc;
        bf16x8 pa0 = *reinterpret_cast<const bf16x8*>(
            Pw + arow * 64 + ((sl ^ (arow & 7)) * 8));
        bf16x8 pa1 = *reinterpret_cast<const bf16x8*>(
            Pw + arow * 64 + (((sl + 4) ^ (arow & 7)) * 8));
        #pragma unroll
        for (int n = 0; n < 4; ++n) {
            int rB = n * 16 + lc;
            bf16x8 v0 = *reinterpret_cast<const bf16x8*>(
                Vs + rB * 64 + ((sl ^ (rB & 7)) * 8));
            bf16x8 v1 = *reinterpret_cast<const bf16x8*>(
                Vs + rB * 64 + (((sl + 4) ^ (rB & 7)) * 8));
            o[n] = __builtin_amdgcn_mfma_f32_16x16x32_bf16(pa0, v0, o[n], 0, 0, 0);
            o[n] = __builtin_amdgcn_mfma_f32_16x16x32_bf16(pa1, v1, o[n], 0, 0, 0);
        }
        __syncthreads();
    }

    int bb = bh >> 2, hh = bh & 3;
    #pragma unroll
    for (int r = 0; r < 4; ++r) {
        float inv = 1.f / l_r[r];
        int ss = qt * 64 + w * 16 + sl * 4 + r;
        #pragma unroll
        for (int n = 0; n < 4; ++n) {
            int dd = n * 16 + lc;
            pv[((size_t)bb * S_ + ss) * D_ + hh * HD_ + dd] = f2b(o[n][r] * inv);
        }
    }
}

// ===========================================================================
extern "C" void kernel_launch(void* const* d_in, const int* in_sizes, int n_in,
                              void* d_out, int out_size, void* d_ws, size_t ws_size,
                              hipStream_t stream)
{
    const int*   tok     = (const int*)  d_in[0];
    const float* ram     = (const float*)d_in[1];
    const float* proj_W  = (const float*)d_in[2];
    const float* proj_b  = (const float*)d_in[3];
    const float* pos_emb = (const float*)d_in[4];
    const float* sa_Wq   = (const float*)d_in[5];
    const float* sa_Wk   = (const float*)d_in[6];
    const float* sa_Wv   = (const float*)d_in[7];
    const float* sa_Wo   = (const float*)d_in[8];
    const float* sa_bq   = (const float*)d_in[9];
    const float* sa_bk   = (const float*)d_in[10];
    const float* sa_bv   = (const float*)d_in[11];
    const float* sa_bo   = (const float*)d_in[12];
    const float* ca_Wo   = (const float*)d_in[16];
    const float* ca_bv   = (const float*)d_in[19];
    const float* ca_bo   = (const float*)d_in[20];
    const float* ln1_s   = (const float*)d_in[21];
    const float* ln1_b   = (const float*)d_in[22];
    const float* ln3_s   = (const float*)d_in[25];
    const float* ln3_b   = (const float*)d_in[26];
    const float* ff_W1   = (const float*)d_in[27];
    const float* ff_b1   = (const float*)d_in[28];
    const float* ff_W2   = (const float*)d_in[29];
    const float* ff_b2   = (const float*)d_in[30];
    const float* out_W   = (const float*)d_in[31];
    const float* out_b   = (const float*)d_in[32];

    float* out = (float*)d_out;
    float* ws  = (float*)d_ws;

    // ws (survives to logits): x | cc | xb | Wb
    float*  x   = ws;                            // BS_*D_ f32
    float*  cc  = ws + (size_t)BS_ * D_;         // L_*D_ f32
    ushort* xb  = (ushort*)(cc + L_ * D_);       // BS_*D_ bf16
    ushort* Wb  = xb + (size_t)BS_ * D_;         // V_*D_ bf16

    // d_out scratch (fully overwritten by the logits GEMM)
    ushort* sc_b  = (ushort*)out;                // 2,097,152
    ushort* h_b   = sc_b + 2097152;              // 1,048,576
    ushort* qkv3  = h_b + 1048576;               // 3,145,728 (q|k|vT)
    ushort* pv_b  = qkv3 + 3145728;              // 1,048,576
    ushort* ffh_b = pv_b + 1048576;              // 2,097,152
    ushort* pjWb  = ffh_b + 2097152;             // 131,072
    ushort* WqkvB = pjWb + 131072;               // 786,432  [L][768][256]
    ushort* WoB   = WqkvB + 786432;              // 262,144
    ushort* ff1B  = WoB + 262144;                // 524,288
    ushort* ff2B  = ff1B + 524288;               // 524,288
    float*  qkvb  = (float*)(ff2B + 524288);     // L*768 f32
    ushort* qb_b  = qkv3;
    ushort* kb_b  = qkv3 + 1048576;
    ushort* vT_b  = qkv3 + 2097152;

    cc_kernel<<<L_, 256, 0, stream>>>(ca_bv, ca_Wo, ca_bo, cc);
    pack_qkv_bias_kernel<<<L_, 768, 0, stream>>>(sa_bq, sa_bk, sa_bv, qkvb);
    embed_bf16_kernel<<<BS_, 256, 0, stream>>>(tok, ram, sc_b);

    dim3 tb(32, 8);
    transpose_bf16_kernel<<<dim3(D_ / 32, NC_ / 32, 1), tb, 0, stream>>>(proj_W, pjWb, NC_, D_);
    transpose_qkv_kernel<<<dim3(D_ / 32, D_ / 32, 3 * L_), tb, 0, stream>>>(sa_Wq, sa_Wk, sa_Wv, WqkvB);
    transpose_bf16_kernel<<<dim3(D_ / 32, D_ / 32, L_), tb, 0, stream>>>(sa_Wo, WoB, D_, D_);
    transpose_bf16_kernel<<<dim3(FF_ / 32, D_ / 32, L_), tb, 0, stream>>>(ff_W1, ff1B, D_, FF_);
    transpose_bf16_kernel<<<dim3(D_ / 32, FF_ / 32, L_), tb, 0, stream>>>(ff_W2, ff2B, FF_, D_);
    transpose_bf16_kernel<<<dim3(V_ / 32, D_ / 32, 1), tb, 0, stream>>>(out_W, Wb, D_, V_);

    // x = scores @ proj_W + proj_b + pos_emb
    gemm_t<64, 64, 512, 256, FG_F32 | FG_POS><<<256, 256, 0, stream>>>(
        sc_b, pjWb, proj_b, nullptr, nullptr, pos_emb, x, nullptr);

    for (int l = 0; l < L_; ++l) {
        ln_bf16_kernel<<<1024, 256, 0, stream>>>(x, ln1_s + l * D_, ln1_b + l * D_, h_b);
        gemm_t<64, 64, 256, 768, FG_QKV><<<768, 256, 0, stream>>>(
            h_b, WqkvB + (size_t)l * 768 * 256, qkvb + l * 768,
            nullptr, nullptr, nullptr, nullptr, qkv3);
        attn_kernel<<<dim3(8, 32), 256, 0, stream>>>(qb_b, kb_b, vT_b, pv_b);
        // x = x + pv @ Wo + bo + cc[l]
        gemm_t<64, 64, 256, 256, FG_F32><<<256, 256, 0, stream>>>(
            pv_b, WoB + (size_t)l * D_ * D_, sa_bo + l * D_,
            cc + l * D_, x, nullptr, x, nullptr);
        ln_bf16_kernel<<<1024, 256, 0, stream>>>(x, ln3_s + l * D_, ln3_b + l * D_, h_b);
        gemm_t<64, 64, 256, 512, FG_BF16 | FG_RELU><<<512, 256, 0, stream>>>(
            h_b, ff1B + (size_t)l * D_ * FF_, ff_b1 + l * FF_,
            nullptr, nullptr, nullptr, nullptr, ffh_b);
        if (l < L_ - 1) {
            gemm_t<64, 64, 512, 256, FG_F32><<<256, 256, 0, stream>>>(
                ffh_b, ff2B + (size_t)l * FF_ * D_, ff_b2 + l * D_,
                nullptr, x, nullptr, x, nullptr);
        } else {
            // last layer: emit x directly as bf16 for the logits GEMM
            gemm_t<64, 64, 512, 256, FG_BF16><<<256, 256, 0, stream>>>(
                ffh_b, ff2B + (size_t)l * FF_ * D_, ff_b2 + l * D_,
                nullptr, x, nullptr, nullptr, xb);
        }
    }

    // logits = xb @ Wb^T + out_b  (overwrites all of d_out)
    gemm_t<128, 128, 256, 32000, FG_F32 | FG_NT><<<8000, 256, 0, stream>>>(
        xb, Wb, out_b, nullptr, nullptr, nullptr, out, nullptr);
}